// Round 12
// baseline (93.367 us; speedup 1.0000x reference)
//
#include <hip/hip_runtime.h>
#include <math.h>

typedef __attribute__((ext_vector_type(8))) short bf16x8;
typedef __attribute__((ext_vector_type(4))) short bf16x4;
typedef __attribute__((ext_vector_type(4))) float f32x4;

__device__ inline ushort f2bf(float f) {
    union { float f; uint u; } v; v.f = f;
    uint u = v.u;
    return (ushort)((u + 0x7fff + ((u >> 16) & 1)) >> 16);   // RNE
}
__device__ inline float bf2f(ushort u) {
    union { uint u; float f; } v; v.u = ((uint)u) << 16; return v.f;
}

typedef __attribute__((address_space(1))) const void global_void;
typedef __attribute__((address_space(3))) void lds_void;
__device__ inline void gl_lds16(const void* g, void* l) {
    __builtin_amdgcn_global_load_lds((global_void*)g, (lds_void*)l, 16, 0, 0);
}

// ---------------------------------------------------------------------------
// MFMA bf16 GEMM, converts inputs on the fly.  (unchanged; passed R3-R11)
// ---------------------------------------------------------------------------
template<int BM, int BN, int WGM, int WGN, int MODE>
__global__ __launch_bounds__(WGM * WGN * 64) void gemm_fused(
    const void* __restrict__ Ap, const float* __restrict__ Bw, int ldb,
    const float* __restrict__ bias,
    void* __restrict__ C0, void* __restrict__ C1, void* __restrict__ C2,
    int K, int N)
{
    constexpr int BK = 32;
    constexpr int NT = WGM * WGN * 64;
    constexpr int WM = BM / (WGM * 16);
    constexpr int WN = BN / (WGN * 16);

    __shared__ ushort As[BM * BK];
    __shared__ ushort Bs[BN * BK];

    const int tid = threadIdx.x;
    const int lane = tid & 63, wid = tid >> 6;
    const int wm = wid / WGN, wn = wid % WGN;
    const int row0 = blockIdx.y * BM, col0 = blockIdx.x * BN;
    const int frow = lane & 15, fg = lane >> 4;

    f32x4 acc[WM][WN] = {};

    for (int k0 = 0; k0 < K; k0 += BK) {
        if constexpr (MODE == 0) {
            #pragma unroll
            for (int ci = tid; ci < BM * 8; ci += NT) {
                int r = ci >> 3, kq = ci & 7, g = kq >> 1;
                float4 v = *(const float4*)((const float*)Ap + (size_t)(row0 + r) * K + k0 + kq * 4);
                bf16x4 o;
                o[0] = (short)f2bf(v.x); o[1] = (short)f2bf(v.y);
                o[2] = (short)f2bf(v.z); o[3] = (short)f2bf(v.w);
                *(bf16x4*)&As[r * 32 + ((g ^ ((r >> 1) & 3)) << 3) + (kq & 1) * 4] = o;
            }
        } else {
            #pragma unroll
            for (int ci = tid; ci < BM * 4; ci += NT) {
                int r = ci >> 2, g = ci & 3;
                bf16x8 v = *(const bf16x8*)((const ushort*)Ap + (size_t)(row0 + r) * K + k0 + g * 8);
                *(bf16x8*)&As[r * 32 + ((g ^ ((r >> 1) & 3)) << 3)] = v;
            }
        }
        #pragma unroll
        for (int ci = tid; ci < BN * 8; ci += NT) {
            int kk = ci & 31, n4 = ci >> 5;
            float4 v = *(const float4*)&Bw[(size_t)(k0 + kk) * ldb + col0 + n4 * 4];
            float vv[4] = {v.x, v.y, v.z, v.w};
            #pragma unroll
            for (int e = 0; e < 4; ++e) {
                int n = n4 * 4 + e;
                Bs[n * 32 + (((kk >> 3) ^ ((n >> 1) & 3)) << 3) + (kk & 7)] = f2bf(vv[e]);
            }
        }
        __syncthreads();

        bf16x8 af[WM], bfr[WN];
        #pragma unroll
        for (int m = 0; m < WM; ++m) {
            int r = (wm * WM + m) * 16 + frow;
            af[m] = *(const bf16x8*)&As[r * 32 + ((fg ^ ((r >> 1) & 3)) << 3)];
        }
        #pragma unroll
        for (int n = 0; n < WN; ++n) {
            int r = (wn * WN + n) * 16 + frow;
            bfr[n] = *(const bf16x8*)&Bs[r * 32 + ((fg ^ ((r >> 1) & 3)) << 3)];
        }
        #pragma unroll
        for (int m = 0; m < WM; ++m)
            #pragma unroll
            for (int n = 0; n < WN; ++n)
                acc[m][n] = __builtin_amdgcn_mfma_f32_16x16x32_bf16(
                    af[m], bfr[n], acc[m][n], 0, 0, 0);
        __syncthreads();
    }

    #pragma unroll
    for (int n = 0; n < WN; ++n) {
        int gcol = col0 + (wn * WN + n) * 16 + frow;
        float bv = bias[gcol];
        if constexpr (MODE == 0) {
            int b = gcol >> 8, c = gcol & 255;
            ushort* dst = (b == 0) ? (ushort*)C0 : (b == 1) ? (ushort*)C1 : (ushort*)C2;
            #pragma unroll
            for (int m = 0; m < WM; ++m) {
                int grow0 = row0 + (wm * WM + m) * 16 + fg * 4;
                #pragma unroll
                for (int r = 0; r < 4; ++r)
                    dst[(size_t)(grow0 + r) * 256 + c] = f2bf(acc[m][n][r] + bv);
            }
        } else {
            float* dst = (float*)C0;
            #pragma unroll
            for (int m = 0; m < WM; ++m) {
                int grow0 = row0 + (wm * WM + m) * 16 + fg * 4;
                #pragma unroll
                for (int r = 0; r < 4; ++r)
                    dst[(size_t)(grow0 + r) * N + gcol] = acc[m][n][r] + bv;
            }
        }
    }
}

// ---------------------------------------------------------------------------
// Fused relational attention, all-linear gll pipeline (no swizzle anywhere).
// Grid 512 (2 blocks/CU), block = 8 items (same bt).
// Lane identity for ALL phases: col = w*64 + L  (== h*32 + d, h = col>>5).
//   - bias: 2 x 32KB f32 LDS slabs, gll-filled with LINEAR per-lane source
//     (16B/lane, perfectly coalesced) and linear dest. Issued at round start,
//     drained by the NEXT round's __syncthreads -> full-round coverage.
//   - k, v, q, mask register-resident in the same col mapping.
//   - scores: serial over j; per j each lane contributes q*(k+bias) for its
//     one element; 5-step shfl_xor butterfly over the 32-lane half reduces;
//     lane keeps s_j when j == its jd. No s-LDS, no mid-round barrier.
//   - breg[32] caches the slab row elements; reused by scores AND PV
//     (PV does zero LDS reads).
//   - output held in a reg, stored right AFTER the next barrier (store-ack
//     never on the critical path).
// LDS reads: b32 at [j*256 + col] -> 2-way (free). One barrier per round.
// ---------------------------------------------------------------------------
__global__ __launch_bounds__(256, 2) void relattn_kernel(
    const ushort* __restrict__ qb, const ushort* __restrict__ kb,
    const ushort* __restrict__ vb, const float* __restrict__ bias,
    const int* __restrict__ mask, ushort* __restrict__ attn_out)
{
    __shared__ float slab[2][8192];        // 2 x 32KB f32 bias slabs (linear)

    const int b = blockIdx.x;              // 0..511
    const int item0 = b << 3;              // 8 items per block
    const int bt = b >> 2;                 // constant across the 8 items
    const int tid = threadIdx.x;
    const int w = tid >> 6, L = tid & 63;
    const int col = w * 64 + L;            // flat (h,d) element this lane owns
    const int jd = L & 31;                 // j this lane owns for softmax
    const int half32 = L & 32;

    // ---- one-time register loads (all in the col mapping) ----
    const bool alive = (mask[bt * 32 + jd] != 0);

    ushort kreg[32], vreg[32];
    #pragma unroll
    for (int j = 0; j < 32; ++j) {
        kreg[j] = kb[(size_t)(bt * 32 + j) * 256 + col];
        vreg[j] = vb[(size_t)(bt * 32 + j) * 256 + col];
    }
    ushort qreg[8];
    #pragma unroll
    for (int it = 0; it < 8; ++it)
        qreg[it] = qb[(size_t)(item0 + it) * 256 + col];

    const float* bbase = bias + (size_t)item0 * 8192;

    // gll stage: wave w fills rows w*8..w*8+8 of the slab, one row per instr.
    // Linear source (lane L reads 16B at row + L*16) and linear dest.
    auto stage = [&](int idx, int buf) {
        const float* bi = bbase + (size_t)idx * 8192;
        #pragma unroll
        for (int jj = 0; jj < 8; ++jj) {
            int j = w * 8 + jj;
            gl_lds16(bi + j * 256 + L * 4, &slab[buf][j * 256]);
        }
    };

    stage(0, 0);

    float oprev = 0.f;
    #pragma unroll
    for (int it = 0; it < 8; ++it) {
        __syncthreads();                   // drains gll(it) (+ prev store)

        if (it > 0)                        // store item it-1 (drains next bar)
            attn_out[(size_t)(item0 + it - 1) * 256 + tid] = f2bf(oprev);
        if (it < 7) stage(it + 1, (it + 1) & 1);   // in flight all round

        const float* cur = slab[it & 1];

        // ---- cache this item's bias column (reused by scores AND PV) ----
        float breg[32];
        #pragma unroll
        for (int j = 0; j < 32; ++j) breg[j] = cur[j * 256 + col];

        // ---- scores: serial j, butterfly reduce over 32-lane half ----
        const float qf = bf2f(qreg[it]);
        float sreg = 0.f;
        #pragma unroll
        for (int j = 0; j < 32; ++j) {
            float part = qf * (bf2f(kreg[j]) + breg[j]);
            part += __shfl_xor(part, 1);
            part += __shfl_xor(part, 2);
            part += __shfl_xor(part, 4);
            part += __shfl_xor(part, 8);
            part += __shfl_xor(part, 16);
            if (j == jd) sreg = part;      // lane (hw, jd) keeps s[h][jd]
        }
        float s = sreg * 0.17677669529663687f;   // 1/sqrt(32)
        s = alive ? s : -__builtin_inff();

        // ---- softmax within the 32-lane j-group ----
        float m = s;
        #pragma unroll
        for (int off = 16; off; off >>= 1) m = fmaxf(m, __shfl_xor(m, off));
        const bool dead = (m == -__builtin_inff());
        float p = alive ? __expf(s - m) : 0.f;
        float l = p;
        #pragma unroll
        for (int off = 16; off; off >>= 1) l += __shfl_xor(l, off);
        float pn = dead ? 0.f : p / l;

        // ---- PV: serial j, p via shfl, bias from breg, v from regs ----
        float o0 = 0.f, o1 = 0.f, o2 = 0.f, o3 = 0.f;
        #pragma unroll
        for (int jq = 0; jq < 8; ++jq) {
            int j0 = jq * 4;
            float pa = __shfl(pn, half32 | (j0 + 0));
            float pb = __shfl(pn, half32 | (j0 + 1));
            float pc = __shfl(pn, half32 | (j0 + 2));
            float pd = __shfl(pn, half32 | (j0 + 3));
            o0 += pa * (bf2f(vreg[j0 + 0]) + breg[j0 + 0]);
            o1 += pb * (bf2f(vreg[j0 + 1]) + breg[j0 + 1]);
            o2 += pc * (bf2f(vreg[j0 + 2]) + breg[j0 + 2]);
            o3 += pd * (bf2f(vreg[j0 + 3]) + breg[j0 + 3]);
        }
        oprev = (o0 + o1) + (o2 + o3);
    }
    attn_out[(size_t)(item0 + 7) * 256 + tid] = f2bf(oprev);
}

extern "C" void kernel_launch(void* const* d_in, const int* in_sizes, int n_in,
                              void* d_out, int out_size, void* d_ws, size_t ws_size,
                              hipStream_t stream) {
    const float* x      = (const float*)d_in[0];   // (4096,256)
    const float* bias_f = (const float*)d_in[1];   // (4096,32,256)
    const int*   mask   = (const int*)d_in[2];     // (4096,)
    const float* w_qkv  = (const float*)d_in[3];   // (256,768)
    const float* b_qkv  = (const float*)d_in[4];   // (768,)
    const float* w_proj = (const float*)d_in[5];   // (256,256)
    const float* b_proj = (const float*)d_in[6];   // (256,)
    float* out = (float*)d_out;                    // (4096,256)

    // workspace: q,k,v,attn_out each 4096*256 bf16 (2 MB) = 8.4 MB total
    ushort* qb = (ushort*)d_ws;
    ushort* kb = qb + (size_t)4096 * 256;
    ushort* vb = kb + (size_t)4096 * 256;
    ushort* ao = vb + (size_t)4096 * 256;

    // qkv = x @ w_qkv + b_qkv  ->  bf16 q/k/v   (M=4096, N=768, K=256)
    gemm_fused<64, 64, 2, 2, 0><<<dim3(12, 64), 256, 0, stream>>>(
        x, w_qkv, 768, b_qkv, qb, kb, vb, 256, 768);

    relattn_kernel<<<512, 256, 0, stream>>>(qb, kb, vb, bias_f, mask, ao);

    // out = attn_out @ w_proj + b_proj   (M=4096, N=256, K=256)
    gemm_fused<32, 64, 1, 4, 1><<<dim3(4, 128), 256, 0, stream>>>(
        ao, w_proj, 256, b_proj, out, nullptr, nullptr, 256, 256);
}

// Round 13
// 78.945 us; speedup vs baseline: 1.1827x; 1.1827x over previous
//
#include <hip/hip_runtime.h>
#include <math.h>

typedef __attribute__((ext_vector_type(8))) short bf16x8;
typedef __attribute__((ext_vector_type(4))) short bf16x4;
typedef __attribute__((ext_vector_type(4))) float f32x4;

__device__ inline ushort f2bf(float f) {
    union { float f; uint u; } v; v.f = f;
    uint u = v.u;
    return (ushort)((u + 0x7fff + ((u >> 16) & 1)) >> 16);   // RNE
}
__device__ inline float bf2f(ushort u) {
    union { uint u; float f; } v; v.u = ((uint)u) << 16; return v.f;
}

// ---------------------------------------------------------------------------
// MFMA bf16 GEMM, converts inputs on the fly.  (unchanged; passed R3-R12)
// ---------------------------------------------------------------------------
template<int BM, int BN, int WGM, int WGN, int MODE>
__global__ __launch_bounds__(WGM * WGN * 64) void gemm_fused(
    const void* __restrict__ Ap, const float* __restrict__ Bw, int ldb,
    const float* __restrict__ bias,
    void* __restrict__ C0, void* __restrict__ C1, void* __restrict__ C2,
    int K, int N)
{
    constexpr int BK = 32;
    constexpr int NT = WGM * WGN * 64;
    constexpr int WM = BM / (WGM * 16);
    constexpr int WN = BN / (WGN * 16);

    __shared__ ushort As[BM * BK];
    __shared__ ushort Bs[BN * BK];

    const int tid = threadIdx.x;
    const int lane = tid & 63, wid = tid >> 6;
    const int wm = wid / WGN, wn = wid % WGN;
    const int row0 = blockIdx.y * BM, col0 = blockIdx.x * BN;
    const int frow = lane & 15, fg = lane >> 4;

    f32x4 acc[WM][WN] = {};

    for (int k0 = 0; k0 < K; k0 += BK) {
        if constexpr (MODE == 0) {
            #pragma unroll
            for (int ci = tid; ci < BM * 8; ci += NT) {
                int r = ci >> 3, kq = ci & 7, g = kq >> 1;
                float4 v = *(const float4*)((const float*)Ap + (size_t)(row0 + r) * K + k0 + kq * 4);
                bf16x4 o;
                o[0] = (short)f2bf(v.x); o[1] = (short)f2bf(v.y);
                o[2] = (short)f2bf(v.z); o[3] = (short)f2bf(v.w);
                *(bf16x4*)&As[r * 32 + ((g ^ ((r >> 1) & 3)) << 3) + (kq & 1) * 4] = o;
            }
        } else {
            #pragma unroll
            for (int ci = tid; ci < BM * 4; ci += NT) {
                int r = ci >> 2, g = ci & 3;
                bf16x8 v = *(const bf16x8*)((const ushort*)Ap + (size_t)(row0 + r) * K + k0 + g * 8);
                *(bf16x8*)&As[r * 32 + ((g ^ ((r >> 1) & 3)) << 3)] = v;
            }
        }
        #pragma unroll
        for (int ci = tid; ci < BN * 8; ci += NT) {
            int kk = ci & 31, n4 = ci >> 5;
            float4 v = *(const float4*)&Bw[(size_t)(k0 + kk) * ldb + col0 + n4 * 4];
            float vv[4] = {v.x, v.y, v.z, v.w};
            #pragma unroll
            for (int e = 0; e < 4; ++e) {
                int n = n4 * 4 + e;
                Bs[n * 32 + (((kk >> 3) ^ ((n >> 1) & 3)) << 3) + (kk & 7)] = f2bf(vv[e]);
            }
        }
        __syncthreads();

        bf16x8 af[WM], bfr[WN];
        #pragma unroll
        for (int m = 0; m < WM; ++m) {
            int r = (wm * WM + m) * 16 + frow;
            af[m] = *(const bf16x8*)&As[r * 32 + ((fg ^ ((r >> 1) & 3)) << 3)];
        }
        #pragma unroll
        for (int n = 0; n < WN; ++n) {
            int r = (wn * WN + n) * 16 + frow;
            bfr[n] = *(const bf16x8*)&Bs[r * 32 + ((fg ^ ((r >> 1) & 3)) << 3)];
        }
        #pragma unroll
        for (int m = 0; m < WM; ++m)
            #pragma unroll
            for (int n = 0; n < WN; ++n)
                acc[m][n] = __builtin_amdgcn_mfma_f32_16x16x32_bf16(
                    af[m], bfr[n], acc[m][n], 0, 0, 0);
        __syncthreads();
    }

    #pragma unroll
    for (int n = 0; n < WN; ++n) {
        int gcol = col0 + (wn * WN + n) * 16 + frow;
        float bv = bias[gcol];
        if constexpr (MODE == 0) {
            int b = gcol >> 8, c = gcol & 255;
            ushort* dst = (b == 0) ? (ushort*)C0 : (b == 1) ? (ushort*)C1 : (ushort*)C2;
            #pragma unroll
            for (int m = 0; m < WM; ++m) {
                int grow0 = row0 + (wm * WM + m) * 16 + fg * 4;
                #pragma unroll
                for (int r = 0; r < 4; ++r)
                    dst[(size_t)(grow0 + r) * 256 + c] = f2bf(acc[m][n][r] + bv);
            }
        } else {
            float* dst = (float*)C0;
            #pragma unroll
            for (int m = 0; m < WM; ++m) {
                int grow0 = row0 + (wm * WM + m) * 16 + fg * 4;
                #pragma unroll
                for (int r = 0; r < 4; ++r)
                    dst[(size_t)(grow0 + r) * N + gcol] = acc[m][n][r] + bv;
            }
        }
    }
}

// ---------------------------------------------------------------------------
// Pass 1: scores + bias bf16 compress. PURE SEQUENTIAL STREAMING PROBE.
// Wave = one item; reads the item's 32 KB bias slab sequentially
// (1 KB/wave-instr, unroll 8 -> ~12 KB in flight per wave; 16 waves/CU).
// Lane = (h = lane>>3, dq = lane&7) owns cols [lane*4, lane*4+4).
// Per j: bias row f32 (1 KB), k row bf16 (512 B) -> 4 FMA -> 3-level
// butterfly over dq -> s[h]; also writes bf16 bias copy (512 B, for pass 2).
// ---------------------------------------------------------------------------
__global__ __launch_bounds__(256, 4) void score_kernel(
    const ushort* __restrict__ qb, const ushort* __restrict__ kb,
    const float* __restrict__ bias, const int* __restrict__ mask,
    float* __restrict__ s_out, ushort* __restrict__ bb)
{
    const int lane = threadIdx.x & 63;
    const int item = (blockIdx.x << 2) | (threadIdx.x >> 6);   // 0..4095
    const int bt = item >> 5;
    const int h = lane >> 3;

    bf16x4 q4 = *(const bf16x4*)(qb + (size_t)item * 256 + lane * 4);
    const float qf0 = bf2f((ushort)q4[0]), qf1 = bf2f((ushort)q4[1]);
    const float qf2 = bf2f((ushort)q4[2]), qf3 = bf2f((ushort)q4[3]);

    const float*  brow  = bias + (size_t)item * 8192;
    ushort*       bbrow = bb   + (size_t)item * 8192;
    float*        srow  = s_out + (size_t)item * 256;
    const ushort* kbase = kb + (size_t)bt * 8192;
    const int*    mbase = mask + bt * 32;

    #pragma unroll 8
    for (int j = 0; j < 32; ++j) {
        float4 b4 = *(const float4*)(brow + j * 256 + lane * 4);
        bf16x4 k4 = *(const bf16x4*)(kbase + j * 256 + lane * 4);
        bf16x4 c4;
        c4[0] = (short)f2bf(b4.x); c4[1] = (short)f2bf(b4.y);
        c4[2] = (short)f2bf(b4.z); c4[3] = (short)f2bf(b4.w);
        *(bf16x4*)(bbrow + j * 256 + lane * 4) = c4;

        float s = qf0 * (bf2f((ushort)k4[0]) + b4.x)
                + qf1 * (bf2f((ushort)k4[1]) + b4.y)
                + qf2 * (bf2f((ushort)k4[2]) + b4.z)
                + qf3 * (bf2f((ushort)k4[3]) + b4.w);
        s += __shfl_xor(s, 1);
        s += __shfl_xor(s, 2);
        s += __shfl_xor(s, 4);
        if ((lane & 7) == 0) {
            const bool alive = (mbase[j] != 0);
            srow[j * 8 + h] = alive ? s * 0.17677669529663687f
                                    : -__builtin_inff();
        }
    }
}

// ---------------------------------------------------------------------------
// Pass 2: softmax + PV from the bf16 bias copy (half bytes, L2/L3-warm).
// Block = one item. Softmax: thread (h=tid>>5, j=tid&31), shfl in 32-groups.
// PV: wave w covers j in [8w, 8w+8); lane L owns cols [L*4, L*4+4);
// per j: bb row (512 B) + v row (512 B) + p broadcast -> 4 FMA.
// Wave partials reduced through LDS.
// ---------------------------------------------------------------------------
__global__ __launch_bounds__(256, 8) void softpv_kernel(
    const ushort* __restrict__ vb, const ushort* __restrict__ bb,
    const float* __restrict__ sp, const int* __restrict__ mask,
    ushort* __restrict__ ao)
{
    __shared__ float xs[256];
    __shared__ float ps[256];
    __shared__ float po[1024];

    const int item = blockIdx.x, bt = item >> 5, tid = threadIdx.x;

    xs[tid] = sp[(size_t)item * 256 + tid];     // s stored as [j][h]
    __syncthreads();

    const int h = tid >> 5, jd = tid & 31;
    float s = xs[jd * 8 + h];
    const bool alive = (mask[bt * 32 + jd] != 0);

    float m = s;
    #pragma unroll
    for (int off = 16; off; off >>= 1) m = fmaxf(m, __shfl_xor(m, off));
    const bool dead = (m == -__builtin_inff());
    float p = alive ? __expf(s - m) : 0.f;
    float l = p;
    #pragma unroll
    for (int off = 16; off; off >>= 1) l += __shfl_xor(l, off);
    ps[tid] = dead ? 0.f : p / l;               // ps[h*32 + j]
    __syncthreads();

    // ---- PV ----
    const int w = tid >> 6, L = tid & 63;
    const int h2 = L >> 3;
    const ushort* vbase = vb + (size_t)bt * 8192;
    const ushort* bbase = bb + (size_t)item * 8192;

    float o0 = 0.f, o1 = 0.f, o2 = 0.f, o3 = 0.f;
    #pragma unroll
    for (int jj = 0; jj < 8; ++jj) {
        int j = w * 8 + jj;
        bf16x4 b4 = *(const bf16x4*)(bbase + j * 256 + L * 4);
        bf16x4 v4 = *(const bf16x4*)(vbase + j * 256 + L * 4);
        float pj = ps[h2 * 32 + j];
        o0 += pj * (bf2f((ushort)v4[0]) + bf2f((ushort)b4[0]));
        o1 += pj * (bf2f((ushort)v4[1]) + bf2f((ushort)b4[1]));
        o2 += pj * (bf2f((ushort)v4[2]) + bf2f((ushort)b4[2]));
        o3 += pj * (bf2f((ushort)v4[3]) + bf2f((ushort)b4[3]));
    }
    po[tid * 4 + 0] = o0;
    po[tid * 4 + 1] = o1;
    po[tid * 4 + 2] = o2;
    po[tid * 4 + 3] = o3;
    __syncthreads();

    float r = po[tid] + po[256 + tid] + po[512 + tid] + po[768 + tid];
    ao[(size_t)item * 256 + tid] = f2bf(r);
}

extern "C" void kernel_launch(void* const* d_in, const int* in_sizes, int n_in,
                              void* d_out, int out_size, void* d_ws, size_t ws_size,
                              hipStream_t stream) {
    const float* x      = (const float*)d_in[0];   // (4096,256)
    const float* bias_f = (const float*)d_in[1];   // (4096,32,256)
    const int*   mask   = (const int*)d_in[2];     // (4096,)
    const float* w_qkv  = (const float*)d_in[3];   // (256,768)
    const float* b_qkv  = (const float*)d_in[4];   // (768,)
    const float* w_proj = (const float*)d_in[5];   // (256,256)
    const float* b_proj = (const float*)d_in[6];   // (256,)
    float* out = (float*)d_out;                    // (4096,256)

    // workspace (bytes): qb 0, kb 2M, vb 4M, ao 6M (bf16 2MB each),
    //   sp 8388608 (f32 4MB), bb 12582912 (bf16 67MB). total ~80MB (<512MB ws)
    char* ws = (char*)d_ws;
    ushort* qb = (ushort*)ws;
    ushort* kb = (ushort*)(ws + 2097152);
    ushort* vb = (ushort*)(ws + 4194304);
    ushort* ao = (ushort*)(ws + 6291456);
    float*  sp = (float*)(ws + 8388608);
    ushort* bb = (ushort*)(ws + 12582912);

    // qkv = x @ w_qkv + b_qkv  ->  bf16 q/k/v   (M=4096, N=768, K=256)
    gemm_fused<64, 64, 2, 2, 0><<<dim3(12, 64), 256, 0, stream>>>(
        x, w_qkv, 768, b_qkv, qb, kb, vb, 256, 768);

    score_kernel<<<1024, 256, 0, stream>>>(qb, kb, bias_f, mask, sp, bb);
    softpv_kernel<<<4096, 256, 0, stream>>>(vb, bb, sp, mask, ao);

    // out = attn_out @ w_proj + b_proj   (M=4096, N=256, K=256)
    gemm_fused<32, 64, 1, 4, 1><<<dim3(4, 128), 256, 0, stream>>>(
        ao, w_proj, 256, b_proj, out, nullptr, nullptr, 256, 256);
}

// Round 14
// 77.472 us; speedup vs baseline: 1.2052x; 1.0190x over previous
//
#include <hip/hip_runtime.h>
#include <math.h>

typedef __attribute__((ext_vector_type(8))) short bf16x8;
typedef __attribute__((ext_vector_type(4))) short bf16x4;
typedef __attribute__((ext_vector_type(4))) float f32x4;

__device__ inline ushort f2bf(float f) {
    union { float f; uint u; } v; v.f = f;
    uint u = v.u;
    return (ushort)((u + 0x7fff + ((u >> 16) & 1)) >> 16);   // RNE
}
__device__ inline float bf2f(ushort u) {
    union { uint u; float f; } v; v.u = ((uint)u) << 16; return v.f;
}

// ---------------------------------------------------------------------------
// MFMA bf16 GEMM, converts inputs on the fly.  (unchanged; passed R3-R13)
// ---------------------------------------------------------------------------
template<int BM, int BN, int WGM, int WGN, int MODE>
__global__ __launch_bounds__(WGM * WGN * 64) void gemm_fused(
    const void* __restrict__ Ap, const float* __restrict__ Bw, int ldb,
    const float* __restrict__ bias,
    void* __restrict__ C0, void* __restrict__ C1, void* __restrict__ C2,
    int K, int N)
{
    constexpr int BK = 32;
    constexpr int NT = WGM * WGN * 64;
    constexpr int WM = BM / (WGM * 16);
    constexpr int WN = BN / (WGN * 16);

    __shared__ ushort As[BM * BK];
    __shared__ ushort Bs[BN * BK];

    const int tid = threadIdx.x;
    const int lane = tid & 63, wid = tid >> 6;
    const int wm = wid / WGN, wn = wid % WGN;
    const int row0 = blockIdx.y * BM, col0 = blockIdx.x * BN;
    const int frow = lane & 15, fg = lane >> 4;

    f32x4 acc[WM][WN] = {};

    for (int k0 = 0; k0 < K; k0 += BK) {
        if constexpr (MODE == 0) {
            #pragma unroll
            for (int ci = tid; ci < BM * 8; ci += NT) {
                int r = ci >> 3, kq = ci & 7, g = kq >> 1;
                float4 v = *(const float4*)((const float*)Ap + (size_t)(row0 + r) * K + k0 + kq * 4);
                bf16x4 o;
                o[0] = (short)f2bf(v.x); o[1] = (short)f2bf(v.y);
                o[2] = (short)f2bf(v.z); o[3] = (short)f2bf(v.w);
                *(bf16x4*)&As[r * 32 + ((g ^ ((r >> 1) & 3)) << 3) + (kq & 1) * 4] = o;
            }
        } else {
            #pragma unroll
            for (int ci = tid; ci < BM * 4; ci += NT) {
                int r = ci >> 2, g = ci & 3;
                bf16x8 v = *(const bf16x8*)((const ushort*)Ap + (size_t)(row0 + r) * K + k0 + g * 8);
                *(bf16x8*)&As[r * 32 + ((g ^ ((r >> 1) & 3)) << 3)] = v;
            }
        }
        #pragma unroll
        for (int ci = tid; ci < BN * 8; ci += NT) {
            int kk = ci & 31, n4 = ci >> 5;
            float4 v = *(const float4*)&Bw[(size_t)(k0 + kk) * ldb + col0 + n4 * 4];
            float vv[4] = {v.x, v.y, v.z, v.w};
            #pragma unroll
            for (int e = 0; e < 4; ++e) {
                int n = n4 * 4 + e;
                Bs[n * 32 + (((kk >> 3) ^ ((n >> 1) & 3)) << 3) + (kk & 7)] = f2bf(vv[e]);
            }
        }
        __syncthreads();

        bf16x8 af[WM], bfr[WN];
        #pragma unroll
        for (int m = 0; m < WM; ++m) {
            int r = (wm * WM + m) * 16 + frow;
            af[m] = *(const bf16x8*)&As[r * 32 + ((fg ^ ((r >> 1) & 3)) << 3)];
        }
        #pragma unroll
        for (int n = 0; n < WN; ++n) {
            int r = (wn * WN + n) * 16 + frow;
            bfr[n] = *(const bf16x8*)&Bs[r * 32 + ((fg ^ ((r >> 1) & 3)) << 3)];
        }
        #pragma unroll
        for (int m = 0; m < WM; ++m)
            #pragma unroll
            for (int n = 0; n < WN; ++n)
                acc[m][n] = __builtin_amdgcn_mfma_f32_16x16x32_bf16(
                    af[m], bfr[n], acc[m][n], 0, 0, 0);
        __syncthreads();
    }

    #pragma unroll
    for (int n = 0; n < WN; ++n) {
        int gcol = col0 + (wn * WN + n) * 16 + frow;
        float bv = bias[gcol];
        if constexpr (MODE == 0) {
            int b = gcol >> 8, c = gcol & 255;
            ushort* dst = (b == 0) ? (ushort*)C0 : (b == 1) ? (ushort*)C1 : (ushort*)C2;
            #pragma unroll
            for (int m = 0; m < WM; ++m) {
                int grow0 = row0 + (wm * WM + m) * 16 + fg * 4;
                #pragma unroll
                for (int r = 0; r < 4; ++r)
                    dst[(size_t)(grow0 + r) * 256 + c] = f2bf(acc[m][n][r] + bv);
            }
        } else {
            float* dst = (float*)C0;
            #pragma unroll
            for (int m = 0; m < WM; ++m) {
                int grow0 = row0 + (wm * WM + m) * 16 + fg * 4;
                #pragma unroll
                for (int r = 0; r < 4; ++r)
                    dst[(size_t)(grow0 + r) * N + gcol] = acc[m][n][r] + bv;
            }
        }
    }
}

// ---------------------------------------------------------------------------
// Fused relational attention, bias register-resident (read ONCE, f32).
// Wave = one item; lane owns cols [lane*4, lane*4+4) (h = lane>>3).
// No LDS, no barriers, no inter-wave coupling.
//   Loop A: issue ALL 32 bias row loads into breg[32] (f32x4 each, static
//           targets) -> up to 32 KB in flight PER WAVE.
//   Loop B: per j: k row from L2 + 4 FMA + 3-level shfl butterfly over the
//           8-lane group (R13-proven shape); lane (j&7) keeps s[h][j].
//   Softmax: in-register over the 8-lane group (4 j's per lane).
//   Phase 2: per j: v row from L2, p via intra-group shfl, FMA against breg.
// ---------------------------------------------------------------------------
__global__ __launch_bounds__(256, 2) void relattn_kernel(
    const ushort* __restrict__ qb, const ushort* __restrict__ kb,
    const ushort* __restrict__ vb, const float* __restrict__ bias,
    const int* __restrict__ mask, ushort* __restrict__ attn_out)
{
    const int lane = threadIdx.x & 63;
    const int item = (blockIdx.x << 2) | (threadIdx.x >> 6);   // 0..4095
    const int bt = item >> 5;
    const int g8 = lane & 0x38;            // 8-lane group base
    const int l8 = lane & 7;               // lane within group

    const float* brow = bias + (size_t)item * 8192;
    const ushort* kbase = kb + (size_t)bt * 8192;
    const ushort* vbase = vb + (size_t)bt * 8192;
    const int* mbase = mask + bt * 32;

    // ---- Loop A: all 32 bias rows -> registers (32 KB/wave in flight) ----
    f32x4 breg[32];
    #pragma unroll
    for (int j = 0; j < 32; ++j)
        breg[j] = *(const f32x4*)(brow + j * 256 + lane * 4);

    // ---- q for this lane's 4 cols ----
    bf16x4 q4 = *(const bf16x4*)(qb + (size_t)item * 256 + lane * 4);
    const float qf0 = bf2f((ushort)q4[0]), qf1 = bf2f((ushort)q4[1]);
    const float qf2 = bf2f((ushort)q4[2]), qf3 = bf2f((ushort)q4[3]);

    // ---- Loop B: scores ----
    float sreg[4];
    #pragma unroll
    for (int j = 0; j < 32; ++j) {
        bf16x4 k4 = *(const bf16x4*)(kbase + j * 256 + lane * 4);
        float part = qf0 * (bf2f((ushort)k4[0]) + breg[j][0])
                   + qf1 * (bf2f((ushort)k4[1]) + breg[j][1])
                   + qf2 * (bf2f((ushort)k4[2]) + breg[j][2])
                   + qf3 * (bf2f((ushort)k4[3]) + breg[j][3]);
        part += __shfl_xor(part, 1);
        part += __shfl_xor(part, 2);
        part += __shfl_xor(part, 4);
        if ((j & 7) == l8)
            sreg[j >> 3] = (mbase[j] != 0) ? part * 0.17677669529663687f
                                           : -__builtin_inff();
    }

    // ---- softmax over the 8-lane group (32 j's) ----
    float m = fmaxf(fmaxf(sreg[0], sreg[1]), fmaxf(sreg[2], sreg[3]));
    m = fmaxf(m, __shfl_xor(m, 1));
    m = fmaxf(m, __shfl_xor(m, 2));
    m = fmaxf(m, __shfl_xor(m, 4));
    const bool dead = (m == -__builtin_inff());
    float p0 = dead ? 0.f : __expf(sreg[0] - m);
    float p1 = dead ? 0.f : __expf(sreg[1] - m);
    float p2 = dead ? 0.f : __expf(sreg[2] - m);
    float p3 = dead ? 0.f : __expf(sreg[3] - m);
    float l = (p0 + p1) + (p2 + p3);
    l += __shfl_xor(l, 1);
    l += __shfl_xor(l, 2);
    l += __shfl_xor(l, 4);
    const float rl = dead ? 0.f : __frcp_rn(l);
    float pn[4] = {p0 * rl, p1 * rl, p2 * rl, p3 * rl};

    // ---- Phase 2: PV against register bias; v from L2 ----
    float o0 = 0.f, o1 = 0.f, o2 = 0.f, o3 = 0.f;
    #pragma unroll
    for (int j = 0; j < 32; ++j) {
        bf16x4 v4 = *(const bf16x4*)(vbase + j * 256 + lane * 4);
        float pj = __shfl(pn[j >> 3], g8 | (j & 7));
        o0 += pj * (bf2f((ushort)v4[0]) + breg[j][0]);
        o1 += pj * (bf2f((ushort)v4[1]) + breg[j][1]);
        o2 += pj * (bf2f((ushort)v4[2]) + breg[j][2]);
        o3 += pj * (bf2f((ushort)v4[3]) + breg[j][3]);
    }
    bf16x4 rr;
    rr[0] = (short)f2bf(o0); rr[1] = (short)f2bf(o1);
    rr[2] = (short)f2bf(o2); rr[3] = (short)f2bf(o3);
    *(bf16x4*)(attn_out + (size_t)item * 256 + lane * 4) = rr;
}

extern "C" void kernel_launch(void* const* d_in, const int* in_sizes, int n_in,
                              void* d_out, int out_size, void* d_ws, size_t ws_size,
                              hipStream_t stream) {
    const float* x      = (const float*)d_in[0];   // (4096,256)
    const float* bias_f = (const float*)d_in[1];   // (4096,32,256)
    const int*   mask   = (const int*)d_in[2];     // (4096,)
    const float* w_qkv  = (const float*)d_in[3];   // (256,768)
    const float* b_qkv  = (const float*)d_in[4];   // (768,)
    const float* w_proj = (const float*)d_in[5];   // (256,256)
    const float* b_proj = (const float*)d_in[6];   // (256,)
    float* out = (float*)d_out;                    // (4096,256)

    // workspace: q,k,v,attn_out each 4096*256 bf16 (2 MB) = 8.4 MB total
    ushort* qb = (ushort*)d_ws;
    ushort* kb = qb + (size_t)4096 * 256;
    ushort* vb = kb + (size_t)4096 * 256;
    ushort* ao = vb + (size_t)4096 * 256;

    // qkv = x @ w_qkv + b_qkv  ->  bf16 q/k/v   (M=4096, N=768, K=256)
    gemm_fused<64, 64, 2, 2, 0><<<dim3(12, 64), 256, 0, stream>>>(
        x, w_qkv, 768, b_qkv, qb, kb, vb, 256, 768);

    relattn_kernel<<<1024, 256, 0, stream>>>(qb, kb, vb, bias_f, mask, ao);

    // out = attn_out @ w_proj + b_proj   (M=4096, N=256, K=256)
    gemm_fused<32, 64, 1, 4, 1><<<dim3(4, 128), 256, 0, stream>>>(
        ao, w_proj, 256, b_proj, out, nullptr, nullptr, 256, 256);
}

// Round 15
// 55.888 us; speedup vs baseline: 1.6706x; 1.3862x over previous
//
#include <hip/hip_runtime.h>
#include <math.h>

typedef __attribute__((ext_vector_type(8))) short bf16x8;
typedef __attribute__((ext_vector_type(4))) short bf16x4;
typedef __attribute__((ext_vector_type(4))) float f32x4;

__device__ inline ushort f2bf(float f) {
    union { float f; uint u; } v; v.f = f;
    uint u = v.u;
    return (ushort)((u + 0x7fff + ((u >> 16) & 1)) >> 16);   // RNE
}
__device__ inline float bf2f(ushort u) {
    union { uint u; float f; } v; v.u = ((uint)u) << 16; return v.f;
}

// ---------------------------------------------------------------------------
// MFMA bf16 GEMM, converts inputs on the fly.  (unchanged; passed R3-R14)
// ---------------------------------------------------------------------------
template<int BM, int BN, int WGM, int WGN, int MODE>
__global__ __launch_bounds__(WGM * WGN * 64) void gemm_fused(
    const void* __restrict__ Ap, const float* __restrict__ Bw, int ldb,
    const float* __restrict__ bias,
    void* __restrict__ C0, void* __restrict__ C1, void* __restrict__ C2,
    int K, int N)
{
    constexpr int BK = 32;
    constexpr int NT = WGM * WGN * 64;
    constexpr int WM = BM / (WGM * 16);
    constexpr int WN = BN / (WGN * 16);

    __shared__ ushort As[BM * BK];
    __shared__ ushort Bs[BN * BK];

    const int tid = threadIdx.x;
    const int lane = tid & 63, wid = tid >> 6;
    const int wm = wid / WGN, wn = wid % WGN;
    const int row0 = blockIdx.y * BM, col0 = blockIdx.x * BN;
    const int frow = lane & 15, fg = lane >> 4;

    f32x4 acc[WM][WN] = {};

    for (int k0 = 0; k0 < K; k0 += BK) {
        if constexpr (MODE == 0) {
            #pragma unroll
            for (int ci = tid; ci < BM * 8; ci += NT) {
                int r = ci >> 3, kq = ci & 7, g = kq >> 1;
                float4 v = *(const float4*)((const float*)Ap + (size_t)(row0 + r) * K + k0 + kq * 4);
                bf16x4 o;
                o[0] = (short)f2bf(v.x); o[1] = (short)f2bf(v.y);
                o[2] = (short)f2bf(v.z); o[3] = (short)f2bf(v.w);
                *(bf16x4*)&As[r * 32 + ((g ^ ((r >> 1) & 3)) << 3) + (kq & 1) * 4] = o;
            }
        } else {
            #pragma unroll
            for (int ci = tid; ci < BM * 4; ci += NT) {
                int r = ci >> 2, g = ci & 3;
                bf16x8 v = *(const bf16x8*)((const ushort*)Ap + (size_t)(row0 + r) * K + k0 + g * 8);
                *(bf16x8*)&As[r * 32 + ((g ^ ((r >> 1) & 3)) << 3)] = v;
            }
        }
        #pragma unroll
        for (int ci = tid; ci < BN * 8; ci += NT) {
            int kk = ci & 31, n4 = ci >> 5;
            float4 v = *(const float4*)&Bw[(size_t)(k0 + kk) * ldb + col0 + n4 * 4];
            float vv[4] = {v.x, v.y, v.z, v.w};
            #pragma unroll
            for (int e = 0; e < 4; ++e) {
                int n = n4 * 4 + e;
                Bs[n * 32 + (((kk >> 3) ^ ((n >> 1) & 3)) << 3) + (kk & 7)] = f2bf(vv[e]);
            }
        }
        __syncthreads();

        bf16x8 af[WM], bfr[WN];
        #pragma unroll
        for (int m = 0; m < WM; ++m) {
            int r = (wm * WM + m) * 16 + frow;
            af[m] = *(const bf16x8*)&As[r * 32 + ((fg ^ ((r >> 1) & 3)) << 3)];
        }
        #pragma unroll
        for (int n = 0; n < WN; ++n) {
            int r = (wn * WN + n) * 16 + frow;
            bfr[n] = *(const bf16x8*)&Bs[r * 32 + ((fg ^ ((r >> 1) & 3)) << 3)];
        }
        #pragma unroll
        for (int m = 0; m < WM; ++m)
            #pragma unroll
            for (int n = 0; n < WN; ++n)
                acc[m][n] = __builtin_amdgcn_mfma_f32_16x16x32_bf16(
                    af[m], bfr[n], acc[m][n], 0, 0, 0);
        __syncthreads();
    }

    #pragma unroll
    for (int n = 0; n < WN; ++n) {
        int gcol = col0 + (wn * WN + n) * 16 + frow;
        float bv = bias[gcol];
        if constexpr (MODE == 0) {
            int b = gcol >> 8, c = gcol & 255;
            ushort* dst = (b == 0) ? (ushort*)C0 : (b == 1) ? (ushort*)C1 : (ushort*)C2;
            #pragma unroll
            for (int m = 0; m < WM; ++m) {
                int grow0 = row0 + (wm * WM + m) * 16 + fg * 4;
                #pragma unroll
                for (int r = 0; r < 4; ++r)
                    dst[(size_t)(grow0 + r) * 256 + c] = f2bf(acc[m][n][r] + bv);
            }
        } else {
            float* dst = (float*)C0;
            #pragma unroll
            for (int m = 0; m < WM; ++m) {
                int grow0 = row0 + (wm * WM + m) * 16 + fg * 4;
                #pragma unroll
                for (int r = 0; r < 4; ++r)
                    dst[(size_t)(grow0 + r) * N + gcol] = acc[m][n][r] + bv;
            }
        }
    }
}

// ---------------------------------------------------------------------------
// Fused relational attention, ONLINE-SOFTMAX single pass (flash-style).
// Exactly the R13 score-kernel streaming shape (proven ~4.1 TB/s):
//   wave = one item; lane owns cols [lane*4, lane*4+4); grid 1024;
//   16 waves/CU; no LDS, no barriers, no bias storage of ANY kind.
// Per j (unroll 8): load bias row f32x4 (1 KB/wave-instr, coalesced),
//   k row bf16x4, v row bf16x4 (L2-hot) ->
//   s_j = sum over 8-lane group of q*(k+b)   (3-level shfl_xor butterfly --
//         leaves the full sum in ALL lanes, no keeper needed)
//   online update: mn = alive ? max(m,s) : m;  c = exp(m-mn);
//                  e  = alive ? exp(s-mn) : 0;
//                  acc = acc*c + e*(v+b);  l = l*c + e;  m = mn.
// Bias element is consumed immediately after load, once, then dead.
// Epilogue: out = acc * (l>0 ? 1/l : 0)  (dead rows -> 0, matches reference).
// Exact softmax math -- no approximation.
// ---------------------------------------------------------------------------
__global__ __launch_bounds__(256, 4) void relattn_kernel(
    const ushort* __restrict__ qb, const ushort* __restrict__ kb,
    const ushort* __restrict__ vb, const float* __restrict__ bias,
    const int* __restrict__ mask, ushort* __restrict__ attn_out)
{
    const int lane = threadIdx.x & 63;
    const int item = (blockIdx.x << 2) | (threadIdx.x >> 6);   // 0..4095
    const int bt = item >> 5;

    const float*  brow  = bias + (size_t)item * 8192;
    const ushort* kbase = kb + (size_t)bt * 8192;
    const ushort* vbase = vb + (size_t)bt * 8192;

    // mask bits for rows 0..31 (one ballot, reused every j)
    const bool myalive = (mask[bt * 32 + (lane & 31)] != 0);
    const uint amask = (uint)__ballot(myalive);

    bf16x4 q4 = *(const bf16x4*)(qb + (size_t)item * 256 + lane * 4);
    const float qf0 = bf2f((ushort)q4[0]), qf1 = bf2f((ushort)q4[1]);
    const float qf2 = bf2f((ushort)q4[2]), qf3 = bf2f((ushort)q4[3]);

    float m = -1e30f, l = 0.f;
    float o0 = 0.f, o1 = 0.f, o2 = 0.f, o3 = 0.f;

    #pragma unroll 8
    for (int j = 0; j < 32; ++j) {
        float4 b4 = *(const float4*)(brow + j * 256 + lane * 4);
        bf16x4 k4 = *(const bf16x4*)(kbase + j * 256 + lane * 4);
        bf16x4 v4 = *(const bf16x4*)(vbase + j * 256 + lane * 4);

        float s = qf0 * (bf2f((ushort)k4[0]) + b4.x)
                + qf1 * (bf2f((ushort)k4[1]) + b4.y)
                + qf2 * (bf2f((ushort)k4[2]) + b4.z)
                + qf3 * (bf2f((ushort)k4[3]) + b4.w);
        s += __shfl_xor(s, 1);
        s += __shfl_xor(s, 2);
        s += __shfl_xor(s, 4);
        s *= 0.17677669529663687f;            // 1/sqrt(32)

        const bool alive = (amask >> j) & 1;
        const float mn = alive ? fmaxf(m, s) : m;
        const float c = __expf(m - mn);       // ==1 when m unchanged
        const float e = alive ? __expf(s - mn) : 0.f;
        o0 = o0 * c + e * (bf2f((ushort)v4[0]) + b4.x);
        o1 = o1 * c + e * (bf2f((ushort)v4[1]) + b4.y);
        o2 = o2 * c + e * (bf2f((ushort)v4[2]) + b4.z);
        o3 = o3 * c + e * (bf2f((ushort)v4[3]) + b4.w);
        l = l * c + e;
        m = mn;
    }

    const float rl = (l > 0.f) ? 1.f / l : 0.f;
    bf16x4 rr;
    rr[0] = (short)f2bf(o0 * rl);
    rr[1] = (short)f2bf(o1 * rl);
    rr[2] = (short)f2bf(o2 * rl);
    rr[3] = (short)f2bf(o3 * rl);
    *(bf16x4*)(attn_out + (size_t)item * 256 + lane * 4) = rr;
}

extern "C" void kernel_launch(void* const* d_in, const int* in_sizes, int n_in,
                              void* d_out, int out_size, void* d_ws, size_t ws_size,
                              hipStream_t stream) {
    const float* x      = (const float*)d_in[0];   // (4096,256)
    const float* bias_f = (const float*)d_in[1];   // (4096,32,256)
    const int*   mask   = (const int*)d_in[2];     // (4096,)
    const float* w_qkv  = (const float*)d_in[3];   // (256,768)
    const float* b_qkv  = (const float*)d_in[4];   // (768,)
    const float* w_proj = (const float*)d_in[5];   // (256,256)
    const float* b_proj = (const float*)d_in[6];   // (256,)
    float* out = (float*)d_out;                    // (4096,256)

    // workspace: q,k,v,attn_out each 4096*256 bf16 (2 MB) = 8.4 MB total
    ushort* qb = (ushort*)d_ws;
    ushort* kb = qb + (size_t)4096 * 256;
    ushort* vb = kb + (size_t)4096 * 256;
    ushort* ao = vb + (size_t)4096 * 256;

    // qkv = x @ w_qkv + b_qkv  ->  bf16 q/k/v   (M=4096, N=768, K=256)
    gemm_fused<64, 64, 2, 2, 0><<<dim3(12, 64), 256, 0, stream>>>(
        x, w_qkv, 768, b_qkv, qb, kb, vb, 256, 768);

    relattn_kernel<<<1024, 256, 0, stream>>>(qb, kb, vb, bias_f, mask, ao);

    // out = attn_out @ w_proj + b_proj   (M=4096, N=256, K=256)
    gemm_fused<32, 64, 1, 4, 1><<<dim3(4, 128), 256, 0, stream>>>(
        ao, w_proj, 256, b_proj, out, nullptr, nullptr, 256, 256);
}